// Round 24
// baseline (185.953 us; speedup 1.0000x reference)
//
#include <hip/hip_runtime.h>
#include <hip/hip_bf16.h>

#define BB 8
#define NN 1024
#define DD 384
#define HH 6
#define HD 64
#define BN 8192          // B*N rows
#define D3 1152          // 3*D
#define D4 1536          // 4*D
#define SEC 3145728      // B*H*N*HD elems per plane

typedef __attribute__((ext_vector_type(8))) short short8;
typedef __attribute__((ext_vector_type(4))) float f32x4;
typedef __attribute__((ext_vector_type(2))) float f32x2;
typedef long v2i64 __attribute__((ext_vector_type(2)));

typedef __attribute__((address_space(3))) unsigned char as3_byte;
typedef __attribute__((address_space(1))) const unsigned char as1_byte;

__device__ __forceinline__ void gload16(const void* g, void* l){
  __builtin_amdgcn_global_load_lds((as1_byte*)g, (as3_byte*)l, 16, 0, 0);
}

__device__ __forceinline__ float b2f(unsigned short u){
  union{unsigned int i; float f;} x; x.i=((unsigned int)u)<<16; return x.f;
}
__device__ __forceinline__ unsigned short f2b(float f){
  unsigned int u=__float_as_uint(f);
  return (unsigned short)((u + 0x7FFFu + ((u>>16)&1u))>>16);
}
__device__ __forceinline__ unsigned char f2f8(float f){
  return (unsigned char)(__builtin_amdgcn_cvt_pk_fp8_f32(f, f, 0, false) & 0xff);
}

// ---------------- weight convert: ALL weights -> fp8 (x8), one launch ----------------
__global__ void cvt_kernel(const float* __restrict__ w0, const float* __restrict__ w1,
                           const float* __restrict__ w2, const float* __restrict__ w3,
                           unsigned char* __restrict__ out8){
  int i = blockIdx.x*256 + threadIdx.x;
  if (i < 442368)        out8[i] = f2f8(w0[i]*8.0f);
  else if (i < 589824)   out8[i] = f2f8(w1[i - 442368]*8.0f);
  else if (i < 1179648)  out8[i] = f2f8(w2[i - 589824]*8.0f);
  else if (i < 1769472)  out8[i] = f2f8(w3[i - 1179648]*8.0f);
}

// ---------------- LayerNorm over D=384, one block per row; OUT8: fp8(x4) else bf16 ----------------
template<int OUT8>
__global__ __launch_bounds__(128)
void ln_kernel(const float* __restrict__ in, const float* __restrict__ gg, const float* __restrict__ bb,
               unsigned short* __restrict__ outb, unsigned char* __restrict__ out8){
  int row = blockIdx.x, t = threadIdx.x;
  const float* r = in + (size_t)row*DD;
  float v0=r[t], v1=r[t+128], v2=r[t+256];
  float s=v0+v1+v2, q=v0*v0+v1*v1+v2*v2;
  #pragma unroll
  for (int o=32;o>0;o>>=1){ s+=__shfl_down(s,o); q+=__shfl_down(q,o); }
  __shared__ float ls[2], lq[2];
  if ((t&63)==0){ ls[t>>6]=s; lq[t>>6]=q; }
  __syncthreads();
  float S=ls[0]+ls[1], Q=lq[0]+lq[1];
  float mean=S*(1.0f/DD);
  float rstd=rsqrtf(Q*(1.0f/DD)-mean*mean+1e-5f);
  float o0=(v0-mean)*rstd*gg[t]+bb[t];
  float o1=(v1-mean)*rstd*gg[t+128]+bb[t+128];
  float o2=(v2-mean)*rstd*gg[t+256]+bb[t+256];
  if (OUT8){
    unsigned char* o=out8+(size_t)row*DD;
    o[t]=f2f8(o0*4.0f); o[t+128]=f2f8(o1*4.0f); o[t+256]=f2f8(o2*4.0f);
  } else {
    unsigned short* o=outb+(size_t)row*DD;
    o[t]=f2b(o0); o[t+128]=f2b(o1); o[t+256]=f2b(o2);
  }
}

// ---------------- depthwise conv1d (K=7) + bias + LayerNorm; bf16 in, fp8(x4) out ----------------
__global__ __launch_bounds__(128)
void conv_ln_kernel(const unsigned short* __restrict__ h2, const float* __restrict__ dww, const float* __restrict__ dwb,
                    const float* __restrict__ gg, const float* __restrict__ bb, unsigned char* __restrict__ out8){
  int row=blockIdx.x, t=threadIdx.x;
  int bi=row>>10, n=row&1023;
  const unsigned short* base = h2 + (size_t)(bi<<10)*DD;
  float a[3];
  #pragma unroll
  for (int j=0;j<3;j++){
    int d=t+j*128;
    float acc=dwb[d];
    #pragma unroll
    for (int k=0;k<7;k++){
      int nn=n+k-3;
      if (nn>=0 && nn<NN) acc += dww[d*7+k]*b2f(base[(size_t)nn*DD + d]);
    }
    a[j]=acc;
  }
  float s=a[0]+a[1]+a[2], q=a[0]*a[0]+a[1]*a[1]+a[2]*a[2];
  #pragma unroll
  for (int o=32;o>0;o>>=1){ s+=__shfl_down(s,o); q+=__shfl_down(q,o); }
  __shared__ float ls[2], lq[2];
  if ((t&63)==0){ ls[t>>6]=s; lq[t>>6]=q; }
  __syncthreads();
  float S=ls[0]+ls[1], Q=lq[0]+lq[1];
  float mean=S*(1.0f/DD);
  float rstd=rsqrtf(Q*(1.0f/DD)-mean*mean+1e-5f);
  unsigned char* o = out8 + (size_t)row*DD;
  #pragma unroll
  for (int j=0;j<3;j++){
    int d=t+j*128;
    o[d]=f2f8(((a[j]-mean)*rstd*gg[d]+bb[d])*4.0f);
  }
}

// ================= fp8 x fp8 GEMM: C = (A8·W8^T)/32 + bias =================
// MODE 0: qkv scatter (q,k -> fp8 frag planes, v -> V8 transposed)
// MODE 1: outf = resid + v   (proj / fc2)
// MODE 2: out8 = fp8(4*gelu(v))   (fc1)
template<int MODE>
__global__ __launch_bounds__(256)
void gemm8_kernel(const unsigned char* __restrict__ A8, const unsigned char* __restrict__ W8,
                  const float* __restrict__ bias, const float* __restrict__ resid,
                  float* __restrict__ outf, unsigned char* __restrict__ out8,
                  unsigned char* __restrict__ qk8out, unsigned char* __restrict__ v8out,
                  int Kdim, int Ncols){
  __shared__ __align__(16) unsigned char As[2][64*64];
  __shared__ __align__(16) unsigned char Bs[2][64*64];
  int t=threadIdx.x, lane=t&63, w=t>>6;
  int bm = blockIdx.x*64;
  int bn = blockIdx.y*64;
  int wr = w>>1, wc = w&1;
  int c16=lane&15, r16=lane>>4;
  f32x4 acc[2][2] = {};
  int arow = t>>2, aslot = (t&3) ^ (arow&3);
  auto stage = [&](int buf, int k0){
    gload16(A8 + (size_t)(bm+arow)*Kdim + k0 + aslot*16, (char*)As + buf*4096 + t*16);
    gload16(W8 + (size_t)(bn+arow)*Kdim + k0 + aslot*16, (char*)Bs + buf*4096 + t*16);
  };
  int niter = Kdim>>6;
  stage(0, 0);
  __syncthreads();
  for (int it=0; it<niter; ++it){
    if (it+1<niter) stage((it+1)&1, (it+1)<<6);
    int off = (it&1)*4096;
    #pragma unroll
    for (int kk=0;kk<2;kk++){
      long afr[2], bfr[2];
      #pragma unroll
      for (int i=0;i<2;i++){
        int ra = wr*32 + i*16 + c16;
        int sa = (kk*2 + (r16>>1)) ^ (ra&3);
        afr[i] = *(const long*)((char*)As + off + ra*64 + (sa<<4) + ((r16&1)<<3));
        int rb = wc*32 + i*16 + c16;
        int sb = (kk*2 + (r16>>1)) ^ (rb&3);
        bfr[i] = *(const long*)((char*)Bs + off + rb*64 + (sb<<4) + ((r16&1)<<3));
      }
      #pragma unroll
      for (int i=0;i<2;i++)
        #pragma unroll
        for (int j=0;j<2;j++)
          acc[i][j] = __builtin_amdgcn_mfma_f32_16x16x32_fp8_fp8(afr[i], bfr[j], acc[i][j], 0,0,0);
    }
    __syncthreads();
  }
  #pragma unroll
  for (int i=0;i<2;i++)
    #pragma unroll
    for (int j=0;j<2;j++)
      #pragma unroll
      for (int r=0;r<4;r++){
        int row = bm + wr*32 + i*16 + r16*4 + r;
        int col = bn + wc*32 + j*16 + c16;
        float v = acc[i][j][r]*0.03125f + bias[col];   // A8=4A, W8=8W -> /32
        if (MODE==0){
          int c = col/384; int rem = col - c*384; int hh = rem>>6, d = rem&63;
          int bi = row>>10, nn = row&1023;
          unsigned char pk = f2f8(v);
          if (c==2){
            v8out[(((size_t)(bi*6+hh))<<16) + ((size_t)d<<10) + nn] = pk;
          } else {
            size_t fa = ((size_t)c*SEC)
                      + ((((size_t)(bi*6+hh))<<6) + (nn>>4))*1024
                      + ((((d>>3)&3)*16 + (nn&15))<<4) + ((d>>5)*8) + (d&7);
            qk8out[fa] = pk;
          }
        } else if (MODE==1){
          size_t idx = (size_t)row*Ncols + col;
          outf[idx] = resid[idx] + v;
        } else {
          float ge = 0.5f*v*(1.0f+erff(v*0.70710678118654752f));
          out8[(size_t)row*Ncols + col] = f2f8(ge*4.0f);
        }
      }
}

// ================= fattn8: fused smx + pvmix. block = (b, 16-row n-tile), 512 blocks, 4 waves =================
// Premix/postmix done in PACKED f32x2 (v_pk_fma_f32): r-pairs processed together, halving VALU FMAs.
// Pass 2 MFMA clusters wrapped in s_setprio(1) (T5). kf register pipeline retained.
__global__ __launch_bounds__(256, 2)
void fattn8_kernel(const unsigned char* __restrict__ qk8, const unsigned char* __restrict__ V8,
                   const float* __restrict__ tbm, const float* __restrict__ tam,
                   unsigned char* __restrict__ outp8){
  __shared__ __align__(16) unsigned char Vs[6*64*64];    // 24 KB
  __shared__ __align__(16) unsigned char pms[6*16*72];   // 6.75 KB, 72B row stride
  __shared__ float lred[4][6][16];
  int t=threadIdx.x, lane=t&63, w=t>>6;
  int b = blockIdx.x&7, nt = blockIdx.x>>3;
  int n0 = nt*16;
  int c16=lane&15, r16=lane>>4;
  const unsigned char* q8f = qk8;
  const unsigned char* k8f = qk8 + SEC;
  v2i64 qf[6];
  #pragma unroll
  for (int h=0;h<6;h++)
    qf[h] = *(const v2i64*)(q8f + (((((size_t)(b*6+h))<<6) + (n0>>4))<<10) + lane*16);
  float tbr[36], tar[36];
  #pragma unroll
  for (int i=0;i<36;i++){ tbr[i]=tbm[i]; tar[i]=tam[i]; }
  const float SC = 0.125f*1.44269504088896f;
  auto stageV = [&](int m0){
    #pragma unroll
    for (int i=0;i<6;i++){
      int u = t + i*256;
      int r = u>>2, s = (u&3) ^ (r&3);
      int g = r>>6, d = r&63;
      gload16(V8 + (((size_t)(b*6+g))<<16) + ((size_t)d<<10) + m0 + s*16,
              (char*)Vs + u*16);
    }
  };
  stageV(0);   // independent of pass 1; drained by the lred barrier
  // ---------------- PASS 1: l over all m (ILP-2, packed premix, no barriers) ----------------
  f32x2 lsum2[6] = {};
  #pragma unroll
  for (int mt=0; mt<8; ++mt){
    int m0a = mt*128 + w*16;
    int m0b = m0a + 64;
    v2i64 kfa[6], kfb[6];
    #pragma unroll
    for (int h=0;h<6;h++)
      kfa[h] = *(const v2i64*)(k8f + (((((size_t)(b*6+h))<<6) + (m0a>>4))<<10) + lane*16);
    #pragma unroll
    for (int h=0;h<6;h++)
      kfb[h] = *(const v2i64*)(k8f + (((((size_t)(b*6+h))<<6) + (m0b>>4))<<10) + lane*16);
    {
      f32x4 aq[6] = {};
      #pragma unroll
      for (int h=0;h<6;h++){
        aq[h] = __builtin_amdgcn_mfma_f32_16x16x32_fp8_fp8(kfa[h][0], qf[h][0], aq[h], 0,0,0);
        aq[h] = __builtin_amdgcn_mfma_f32_16x16x32_fp8_fp8(kfa[h][1], qf[h][1], aq[h], 0,0,0);
      }
      #pragma unroll
      for (int rp=0;rp<2;rp++){
        f32x2 sv0={aq[0][2*rp],aq[0][2*rp+1]}, sv1={aq[1][2*rp],aq[1][2*rp+1]},
              sv2={aq[2][2*rp],aq[2][2*rp+1]}, sv3={aq[3][2*rp],aq[3][2*rp+1]},
              sv4={aq[4][2*rp],aq[4][2*rp+1]}, sv5={aq[5][2*rp],aq[5][2*rp+1]};
        #pragma unroll
        for (int g=0;g<6;g++){
          f32x2 sm2 = tbr[g*6]*sv0 + tbr[g*6+1]*sv1 + tbr[g*6+2]*sv2
                    + tbr[g*6+3]*sv3 + tbr[g*6+4]*sv4 + tbr[g*6+5]*sv5;
          f32x2 e2 = { __builtin_amdgcn_exp2f(sm2.x*SC), __builtin_amdgcn_exp2f(sm2.y*SC) };
          lsum2[g] += e2;
        }
      }
    }
    {
      f32x4 aq[6] = {};
      #pragma unroll
      for (int h=0;h<6;h++){
        aq[h] = __builtin_amdgcn_mfma_f32_16x16x32_fp8_fp8(kfb[h][0], qf[h][0], aq[h], 0,0,0);
        aq[h] = __builtin_amdgcn_mfma_f32_16x16x32_fp8_fp8(kfb[h][1], qf[h][1], aq[h], 0,0,0);
      }
      #pragma unroll
      for (int rp=0;rp<2;rp++){
        f32x2 sv0={aq[0][2*rp],aq[0][2*rp+1]}, sv1={aq[1][2*rp],aq[1][2*rp+1]},
              sv2={aq[2][2*rp],aq[2][2*rp+1]}, sv3={aq[3][2*rp],aq[3][2*rp+1]},
              sv4={aq[4][2*rp],aq[4][2*rp+1]}, sv5={aq[5][2*rp],aq[5][2*rp+1]};
        #pragma unroll
        for (int g=0;g<6;g++){
          f32x2 sm2 = tbr[g*6]*sv0 + tbr[g*6+1]*sv1 + tbr[g*6+2]*sv2
                    + tbr[g*6+3]*sv3 + tbr[g*6+4]*sv4 + tbr[g*6+5]*sv5;
          f32x2 e2 = { __builtin_amdgcn_exp2f(sm2.x*SC), __builtin_amdgcn_exp2f(sm2.y*SC) };
          lsum2[g] += e2;
        }
      }
    }
  }
  float lsum[6];
  #pragma unroll
  for (int g=0;g<6;g++){
    float x = lsum2[g].x + lsum2[g].y;
    x += __shfl_xor(x,16);
    x += __shfl_xor(x,32);
    lsum[g] = x;
  }
  if (r16==0){
    #pragma unroll
    for (int g=0;g<6;g++) lred[w][g][c16] = lsum[g];
  }
  __syncthreads();      // lred visible; stageV(0) drained
  float invl[6];
  #pragma unroll
  for (int g=0;g<6;g++)
    invl[g] = 256.0f/(lred[0][g][c16]+lred[1][g][c16]+lred[2][g][c16]+lred[3][g][c16]);
  // ---------------- PASS 2: recompute + packed mix + PV, kf register-pipelined ----------------
  f32x4 acc[6] = {};
  int pmoff = (((w*2+(r16>>1))<<3) ^ ((c16&7)<<3)) + ((r16&1)<<2);
  v2i64 kfc[6], kfn[6];
  #pragma unroll
  for (int h=0;h<6;h++)
    kfc[h] = *(const v2i64*)(k8f + (((((size_t)(b*6+h))<<6) + ((w*16)>>4))<<10) + lane*16);
  for (int mt=0; mt<16; ++mt){
    if (mt<15){
      int m1 = (mt+1)*64 + w*16;
      #pragma unroll
      for (int h=0;h<6;h++)
        kfn[h] = *(const v2i64*)(k8f + (((((size_t)(b*6+h))<<6) + (m1>>4))<<10) + lane*16);
    }
    f32x4 aq[6] = {};
    __builtin_amdgcn_s_setprio(1);
    #pragma unroll
    for (int h=0;h<6;h++){
      aq[h] = __builtin_amdgcn_mfma_f32_16x16x32_fp8_fp8(kfc[h][0], qf[h][0], aq[h], 0,0,0);
      aq[h] = __builtin_amdgcn_mfma_f32_16x16x32_fp8_fp8(kfc[h][1], qf[h][1], aq[h], 0,0,0);
    }
    __builtin_amdgcn_s_setprio(0);
    f32x2 pmv[6][2];
    #pragma unroll
    for (int rp=0;rp<2;rp++){
      f32x2 sv0={aq[0][2*rp],aq[0][2*rp+1]}, sv1={aq[1][2*rp],aq[1][2*rp+1]},
            sv2={aq[2][2*rp],aq[2][2*rp+1]}, sv3={aq[3][2*rp],aq[3][2*rp+1]},
            sv4={aq[4][2*rp],aq[4][2*rp+1]}, sv5={aq[5][2*rp],aq[5][2*rp+1]};
      f32x2 eg0, eg1, eg2v, eg3, eg4, eg5;
      {
        f32x2 sm2;
        sm2 = tbr[0]*sv0 + tbr[1]*sv1 + tbr[2]*sv2 + tbr[3]*sv3 + tbr[4]*sv4 + tbr[5]*sv5;
        eg0 = f32x2{__builtin_amdgcn_exp2f(sm2.x*SC), __builtin_amdgcn_exp2f(sm2.y*SC)} * invl[0];
        sm2 = tbr[6]*sv0 + tbr[7]*sv1 + tbr[8]*sv2 + tbr[9]*sv3 + tbr[10]*sv4 + tbr[11]*sv5;
        eg1 = f32x2{__builtin_amdgcn_exp2f(sm2.x*SC), __builtin_amdgcn_exp2f(sm2.y*SC)} * invl[1];
        sm2 = tbr[12]*sv0 + tbr[13]*sv1 + tbr[14]*sv2 + tbr[15]*sv3 + tbr[16]*sv4 + tbr[17]*sv5;
        eg2v = f32x2{__builtin_amdgcn_exp2f(sm2.x*SC), __builtin_amdgcn_exp2f(sm2.y*SC)} * invl[2];
        sm2 = tbr[18]*sv0 + tbr[19]*sv1 + tbr[20]*sv2 + tbr[21]*sv3 + tbr[22]*sv4 + tbr[23]*sv5;
        eg3 = f32x2{__builtin_amdgcn_exp2f(sm2.x*SC), __builtin_amdgcn_exp2f(sm2.y*SC)} * invl[3];
        sm2 = tbr[24]*sv0 + tbr[25]*sv1 + tbr[26]*sv2 + tbr[27]*sv3 + tbr[28]*sv4 + tbr[29]*sv5;
        eg4 = f32x2{__builtin_amdgcn_exp2f(sm2.x*SC), __builtin_amdgcn_exp2f(sm2.y*SC)} * invl[4];
        sm2 = tbr[30]*sv0 + tbr[31]*sv1 + tbr[32]*sv2 + tbr[33]*sv3 + tbr[34]*sv4 + tbr[35]*sv5;
        eg5 = f32x2{__builtin_amdgcn_exp2f(sm2.x*SC), __builtin_amdgcn_exp2f(sm2.y*SC)} * invl[5];
      }
      #pragma unroll
      for (int g2=0;g2<6;g2++)
        pmv[g2][rp] = tar[g2*6]*eg0 + tar[g2*6+1]*eg1 + tar[g2*6+2]*eg2v
                    + tar[g2*6+3]*eg3 + tar[g2*6+4]*eg4 + tar[g2*6+5]*eg5;
    }
    #pragma unroll
    for (int g2=0;g2<6;g2++){
      int d0 = __builtin_amdgcn_cvt_pk_fp8_f32(pmv[g2][0].x, pmv[g2][0].y, 0, false);
      d0 = __builtin_amdgcn_cvt_pk_fp8_f32(pmv[g2][1].x, pmv[g2][1].y, d0, true);
      *(unsigned int*)(pms + (g2*16 + c16)*72 + pmoff) = (unsigned int)d0;
    }
    __syncthreads();                 // pms complete; prior stageV drained
    __builtin_amdgcn_s_setprio(1);
    #pragma unroll
    for (int g=0;g<6;g++){
      int arow = g*16 + c16;
      int vrow = g*64 + w*16 + c16;
      #pragma unroll
      for (int kk=0;kk<2;kk++){
        long af = *(const long*)(pms + arow*72 + ((kk*32 + r16*8) ^ ((c16&7)<<3)));
        long bf = *(const long*)(Vs + vrow*64
                   + ((((kk*2 + (r16>>1)) ^ (vrow&3))<<4) + ((r16&1)<<3)));
        acc[g] = __builtin_amdgcn_mfma_f32_16x16x32_fp8_fp8(af, bf, acc[g], 0,0,0);
      }
    }
    __builtin_amdgcn_s_setprio(0);
    __syncthreads();                 // pms/Vs reads done
    if (mt<15) stageV((mt+1)*64);
    #pragma unroll
    for (int h=0;h<6;h++) kfc[h] = kfn[h];
  }
  #pragma unroll
  for (int g=0;g<6;g++)
    #pragma unroll
    for (int r=0;r<4;r++){
      int n = n0 + r16*4 + r;
      int d = g*64 + w*16 + c16;
      outp8[((size_t)(b*1024 + n))*DD + d] = f2f8(acc[g][r] * 0.015625f);  // /256 then x4
    }
}

extern "C" void kernel_launch(void* const* d_in, const int* in_sizes, int n_in,
                              void* d_out, int out_size, void* d_ws, size_t ws_size,
                              hipStream_t stream){
  const float* x      = (const float*)d_in[0];
  const float* qkv_w  = (const float*)d_in[1];
  const float* qkv_b  = (const float*)d_in[2];
  const float* proj_w = (const float*)d_in[3];
  const float* proj_b = (const float*)d_in[4];
  const float* t_before=(const float*)d_in[5];
  const float* t_after =(const float*)d_in[6];
  const float* dw_w   = (const float*)d_in[7];
  const float* dw_b   = (const float*)d_in[8];
  const float* mlp_g  = (const float*)d_in[9];
  const float* mlp_b  = (const float*)d_in[10];
  const float* n1_g   = (const float*)d_in[11];
  const float* n1_b   = (const float*)d_in[12];
  const float* n2_g   = (const float*)d_in[13];
  const float* n2_b   = (const float*)d_in[14];
  const float* fc1_w  = (const float*)d_in[15];
  const float* fc1_b  = (const float*)d_in[16];
  const float* fc2_w  = (const float*)d_in[17];
  const float* fc2_b  = (const float*)d_in[18];
  float* out = (float*)d_out;
  char* ws = (char*)d_ws;
  unsigned char*  qkvw8 = (unsigned char*)(ws + 0);           // 442368
  unsigned char*  projw8= (unsigned char*)(ws + 442368);      // 147456
  unsigned char*  fc1w8 = (unsigned char*)(ws + 589824);      // 589824
  unsigned char*  fc2w8 = (unsigned char*)(ws + 1179648);     // 589824
  unsigned char*  hb8   = (unsigned char*)(ws + 1769472);     // 8192*384 fp8 (reuse: hcln8)
  unsigned char*  qk8   = (unsigned char*)(ws + 4915200);     // 2*SEC fp8 frag planes (reuse: h2 bf16)
  unsigned char*  V8    = (unsigned char*)(ws + 11206656);    // 48*64*1024 fp8
  unsigned char*  fc1o8 = (unsigned char*)(ws + 14745600);    // 8192*1536 fp8
  unsigned char*  attnb8= (unsigned char*)(ws + 65077248);    // 8192*384 fp8
  float*          x2    = (float*)        (ws + 68222976);    // 8192*384 f32
  unsigned short* h2 = (unsigned short*)qk8;
  unsigned char*  hcln8 = hb8;

  cvt_kernel<<<6912,256,0,stream>>>(qkv_w, proj_w, fc1_w, fc2_w, qkvw8);

  ln_kernel<1><<<BN,128,0,stream>>>(x, n1_g, n1_b, nullptr, hb8);
  { dim3 g(BN/64, D3/64); gemm8_kernel<0><<<g,256,0,stream>>>(hb8, qkvw8, qkv_b, nullptr, nullptr, nullptr, qk8, V8, DD, D3); }
  fattn8_kernel<<<512,256,0,stream>>>(qk8, V8, t_before, t_after, attnb8);
  { dim3 g(BN/64, DD/64); gemm8_kernel<1><<<g,256,0,stream>>>(attnb8, projw8, proj_b, x, x2, nullptr, nullptr, nullptr, DD, DD); }
  ln_kernel<0><<<BN,128,0,stream>>>(x2, n2_g, n2_b, h2, nullptr);
  conv_ln_kernel<<<BN,128,0,stream>>>(h2, dw_w, dw_b, mlp_g, mlp_b, hcln8);
  { dim3 g(BN/64, D4/64); gemm8_kernel<2><<<g,256,0,stream>>>(hcln8, fc1w8, fc1_b, nullptr, nullptr, fc1o8, nullptr, nullptr, DD, D4); }
  { dim3 g(BN/64, DD/64); gemm8_kernel<1><<<g,256,0,stream>>>(fc1o8, fc2w8, fc2_b, x2, out, nullptr, nullptr, nullptr, D4, DD); }
}

// Round 25
// 180.748 us; speedup vs baseline: 1.0288x; 1.0288x over previous
//
#include <hip/hip_runtime.h>
#include <hip/hip_bf16.h>

#define BB 8
#define NN 1024
#define DD 384
#define HH 6
#define HD 64
#define BN 8192          // B*N rows
#define D3 1152          // 3*D
#define D4 1536          // 4*D
#define SEC 3145728      // B*H*N*HD elems per plane

typedef __attribute__((ext_vector_type(8))) short short8;
typedef __attribute__((ext_vector_type(4))) float f32x4;
typedef __attribute__((ext_vector_type(2))) float f32x2;
typedef long v2i64 __attribute__((ext_vector_type(2)));

typedef __attribute__((address_space(3))) unsigned char as3_byte;
typedef __attribute__((address_space(1))) const unsigned char as1_byte;

__device__ __forceinline__ void gload16(const void* g, void* l){
  __builtin_amdgcn_global_load_lds((as1_byte*)g, (as3_byte*)l, 16, 0, 0);
}

__device__ __forceinline__ float b2f(unsigned short u){
  union{unsigned int i; float f;} x; x.i=((unsigned int)u)<<16; return x.f;
}
__device__ __forceinline__ unsigned short f2b(float f){
  unsigned int u=__float_as_uint(f);
  return (unsigned short)((u + 0x7FFFu + ((u>>16)&1u))>>16);
}
__device__ __forceinline__ unsigned char f2f8(float f){
  return (unsigned char)(__builtin_amdgcn_cvt_pk_fp8_f32(f, f, 0, false) & 0xff);
}

// ---------------- weight convert: ALL weights -> fp8 (x8), one launch ----------------
__global__ void cvt_kernel(const float* __restrict__ w0, const float* __restrict__ w1,
                           const float* __restrict__ w2, const float* __restrict__ w3,
                           unsigned char* __restrict__ out8){
  int i = blockIdx.x*256 + threadIdx.x;
  if (i < 442368)        out8[i] = f2f8(w0[i]*8.0f);
  else if (i < 589824)   out8[i] = f2f8(w1[i - 442368]*8.0f);
  else if (i < 1179648)  out8[i] = f2f8(w2[i - 589824]*8.0f);
  else if (i < 1769472)  out8[i] = f2f8(w3[i - 1179648]*8.0f);
}

// ---------------- LayerNorm over D=384, one block per row; OUT8: fp8(x4) else bf16 ----------------
template<int OUT8>
__global__ __launch_bounds__(128)
void ln_kernel(const float* __restrict__ in, const float* __restrict__ gg, const float* __restrict__ bb,
               unsigned short* __restrict__ outb, unsigned char* __restrict__ out8){
  int row = blockIdx.x, t = threadIdx.x;
  const float* r = in + (size_t)row*DD;
  float v0=r[t], v1=r[t+128], v2=r[t+256];
  float s=v0+v1+v2, q=v0*v0+v1*v1+v2*v2;
  #pragma unroll
  for (int o=32;o>0;o>>=1){ s+=__shfl_down(s,o); q+=__shfl_down(q,o); }
  __shared__ float ls[2], lq[2];
  if ((t&63)==0){ ls[t>>6]=s; lq[t>>6]=q; }
  __syncthreads();
  float S=ls[0]+ls[1], Q=lq[0]+lq[1];
  float mean=S*(1.0f/DD);
  float rstd=rsqrtf(Q*(1.0f/DD)-mean*mean+1e-5f);
  float o0=(v0-mean)*rstd*gg[t]+bb[t];
  float o1=(v1-mean)*rstd*gg[t+128]+bb[t+128];
  float o2=(v2-mean)*rstd*gg[t+256]+bb[t+256];
  if (OUT8){
    unsigned char* o=out8+(size_t)row*DD;
    o[t]=f2f8(o0*4.0f); o[t+128]=f2f8(o1*4.0f); o[t+256]=f2f8(o2*4.0f);
  } else {
    unsigned short* o=outb+(size_t)row*DD;
    o[t]=f2b(o0); o[t+128]=f2b(o1); o[t+256]=f2b(o2);
  }
}

// ---------------- depthwise conv1d (K=7) + bias + LayerNorm; bf16 in, fp8(x4) out ----------------
__global__ __launch_bounds__(128)
void conv_ln_kernel(const unsigned short* __restrict__ h2, const float* __restrict__ dww, const float* __restrict__ dwb,
                    const float* __restrict__ gg, const float* __restrict__ bb, unsigned char* __restrict__ out8){
  int row=blockIdx.x, t=threadIdx.x;
  int bi=row>>10, n=row&1023;
  const unsigned short* base = h2 + (size_t)(bi<<10)*DD;
  float a[3];
  #pragma unroll
  for (int j=0;j<3;j++){
    int d=t+j*128;
    float acc=dwb[d];
    #pragma unroll
    for (int k=0;k<7;k++){
      int nn=n+k-3;
      if (nn>=0 && nn<NN) acc += dww[d*7+k]*b2f(base[(size_t)nn*DD + d]);
    }
    a[j]=acc;
  }
  float s=a[0]+a[1]+a[2], q=a[0]*a[0]+a[1]*a[1]+a[2]*a[2];
  #pragma unroll
  for (int o=32;o>0;o>>=1){ s+=__shfl_down(s,o); q+=__shfl_down(q,o); }
  __shared__ float ls[2], lq[2];
  if ((t&63)==0){ ls[t>>6]=s; lq[t>>6]=q; }
  __syncthreads();
  float S=ls[0]+ls[1], Q=lq[0]+lq[1];
  float mean=S*(1.0f/DD);
  float rstd=rsqrtf(Q*(1.0f/DD)-mean*mean+1e-5f);
  unsigned char* o = out8 + (size_t)row*DD;
  #pragma unroll
  for (int j=0;j<3;j++){
    int d=t+j*128;
    o[d]=f2f8(((a[j]-mean)*rstd*gg[d]+bb[d])*4.0f);
  }
}

// ================= fp8 x fp8 GEMM: C = (A8·W8^T)/32 + bias =================
// MODE 0: qkv scatter (q,k -> fp8 frag planes, v -> V8 transposed)
// MODE 1: outf = resid + v   (proj / fc2)
// MODE 2: out8 = fp8(4*gelu(v))   (fc1)
template<int MODE>
__global__ __launch_bounds__(256)
void gemm8_kernel(const unsigned char* __restrict__ A8, const unsigned char* __restrict__ W8,
                  const float* __restrict__ bias, const float* __restrict__ resid,
                  float* __restrict__ outf, unsigned char* __restrict__ out8,
                  unsigned char* __restrict__ qk8out, unsigned char* __restrict__ v8out,
                  int Kdim, int Ncols){
  __shared__ __align__(16) unsigned char As[2][64*64];
  __shared__ __align__(16) unsigned char Bs[2][64*64];
  int t=threadIdx.x, lane=t&63, w=t>>6;
  int bm = blockIdx.x*64;
  int bn = blockIdx.y*64;
  int wr = w>>1, wc = w&1;
  int c16=lane&15, r16=lane>>4;
  f32x4 acc[2][2] = {};
  int arow = t>>2, aslot = (t&3) ^ (arow&3);
  auto stage = [&](int buf, int k0){
    gload16(A8 + (size_t)(bm+arow)*Kdim + k0 + aslot*16, (char*)As + buf*4096 + t*16);
    gload16(W8 + (size_t)(bn+arow)*Kdim + k0 + aslot*16, (char*)Bs + buf*4096 + t*16);
  };
  int niter = Kdim>>6;
  stage(0, 0);
  __syncthreads();
  for (int it=0; it<niter; ++it){
    if (it+1<niter) stage((it+1)&1, (it+1)<<6);
    int off = (it&1)*4096;
    #pragma unroll
    for (int kk=0;kk<2;kk++){
      long afr[2], bfr[2];
      #pragma unroll
      for (int i=0;i<2;i++){
        int ra = wr*32 + i*16 + c16;
        int sa = (kk*2 + (r16>>1)) ^ (ra&3);
        afr[i] = *(const long*)((char*)As + off + ra*64 + (sa<<4) + ((r16&1)<<3));
        int rb = wc*32 + i*16 + c16;
        int sb = (kk*2 + (r16>>1)) ^ (rb&3);
        bfr[i] = *(const long*)((char*)Bs + off + rb*64 + (sb<<4) + ((r16&1)<<3));
      }
      #pragma unroll
      for (int i=0;i<2;i++)
        #pragma unroll
        for (int j=0;j<2;j++)
          acc[i][j] = __builtin_amdgcn_mfma_f32_16x16x32_fp8_fp8(afr[i], bfr[j], acc[i][j], 0,0,0);
    }
    __syncthreads();
  }
  #pragma unroll
  for (int i=0;i<2;i++)
    #pragma unroll
    for (int j=0;j<2;j++)
      #pragma unroll
      for (int r=0;r<4;r++){
        int row = bm + wr*32 + i*16 + r16*4 + r;
        int col = bn + wc*32 + j*16 + c16;
        float v = acc[i][j][r]*0.03125f + bias[col];   // A8=4A, W8=8W -> /32
        if (MODE==0){
          int c = col/384; int rem = col - c*384; int hh = rem>>6, d = rem&63;
          int bi = row>>10, nn = row&1023;
          unsigned char pk = f2f8(v);
          if (c==2){
            v8out[(((size_t)(bi*6+hh))<<16) + ((size_t)d<<10) + nn] = pk;
          } else {
            size_t fa = ((size_t)c*SEC)
                      + ((((size_t)(bi*6+hh))<<6) + (nn>>4))*1024
                      + ((((d>>3)&3)*16 + (nn&15))<<4) + ((d>>5)*8) + (d&7);
            qk8out[fa] = pk;
          }
        } else if (MODE==1){
          size_t idx = (size_t)row*Ncols + col;
          outf[idx] = resid[idx] + v;
        } else {
          float ge = 0.5f*v*(1.0f+erff(v*0.70710678118654752f));
          out8[(size_t)row*Ncols + col] = f2f8(ge*4.0f);
        }
      }
}

// ================= fattn8: fused smx + pvmix. block = (b, 16-row n-tile), 512 blocks, 4 waves =================
// Pass 1: ILP-2 QK^T+premix+exp -> lsum, no barriers. Pass 2: per 64-m tile recompute + mix -> pms,
// PV MFMA; kf loads for tile mt+1 PREFETCHED before tile mt's VALU/PV phase (reg-pipelined, named
// arrays, statically indexed; launch_bounds(256,2) caps VGPR at 256 -> no spill).
__global__ __launch_bounds__(256, 2)
void fattn8_kernel(const unsigned char* __restrict__ qk8, const unsigned char* __restrict__ V8,
                   const float* __restrict__ tbm, const float* __restrict__ tam,
                   unsigned char* __restrict__ outp8){
  __shared__ __align__(16) unsigned char Vs[6*64*64];    // 24 KB
  __shared__ __align__(16) unsigned char pms[6*16*72];   // 6.75 KB, 72B row stride
  __shared__ float lred[4][6][16];
  int t=threadIdx.x, lane=t&63, w=t>>6;
  int b = blockIdx.x&7, nt = blockIdx.x>>3;
  int n0 = nt*16;
  int c16=lane&15, r16=lane>>4;
  const unsigned char* q8f = qk8;
  const unsigned char* k8f = qk8 + SEC;
  v2i64 qf[6];
  #pragma unroll
  for (int h=0;h<6;h++)
    qf[h] = *(const v2i64*)(q8f + (((((size_t)(b*6+h))<<6) + (n0>>4))<<10) + lane*16);
  float tbr[36], tar[36];
  #pragma unroll
  for (int i=0;i<36;i++){ tbr[i]=tbm[i]; tar[i]=tam[i]; }
  const float SC = 0.125f*1.44269504088896f;
  auto stageV = [&](int m0){
    #pragma unroll
    for (int i=0;i<6;i++){
      int u = t + i*256;
      int r = u>>2, s = (u&3) ^ (r&3);
      int g = r>>6, d = r&63;
      gload16(V8 + (((size_t)(b*6+g))<<16) + ((size_t)d<<10) + m0 + s*16,
              (char*)Vs + u*16);
    }
  };
  stageV(0);   // independent of pass 1; drained by the lred barrier
  // ---------------- PASS 1: l over all m (ILP-2, no stores, no barriers) ----------------
  float lsum[6]={0.f,0.f,0.f,0.f,0.f,0.f};
  #pragma unroll
  for (int mt=0; mt<8; ++mt){
    int m0a = mt*128 + w*16;
    int m0b = m0a + 64;
    v2i64 kfa[6], kfb[6];
    #pragma unroll
    for (int h=0;h<6;h++)
      kfa[h] = *(const v2i64*)(k8f + (((((size_t)(b*6+h))<<6) + (m0a>>4))<<10) + lane*16);
    #pragma unroll
    for (int h=0;h<6;h++)
      kfb[h] = *(const v2i64*)(k8f + (((((size_t)(b*6+h))<<6) + (m0b>>4))<<10) + lane*16);
    {
      f32x4 aq[6] = {};
      #pragma unroll
      for (int h=0;h<6;h++){
        aq[h] = __builtin_amdgcn_mfma_f32_16x16x32_fp8_fp8(kfa[h][0], qf[h][0], aq[h], 0,0,0);
        aq[h] = __builtin_amdgcn_mfma_f32_16x16x32_fp8_fp8(kfa[h][1], qf[h][1], aq[h], 0,0,0);
      }
      #pragma unroll
      for (int r=0;r<4;r++){
        float s0=aq[0][r], s1=aq[1][r], s2=aq[2][r],
              s3=aq[3][r], s4=aq[4][r], s5=aq[5][r];
        #pragma unroll
        for (int g=0;g<6;g++){
          float sm = tbr[g*6]*s0 + tbr[g*6+1]*s1 + tbr[g*6+2]*s2
                   + tbr[g*6+3]*s3 + tbr[g*6+4]*s4 + tbr[g*6+5]*s5;
          lsum[g] += __builtin_amdgcn_exp2f(sm*SC);
        }
      }
    }
    {
      f32x4 aq[6] = {};
      #pragma unroll
      for (int h=0;h<6;h++){
        aq[h] = __builtin_amdgcn_mfma_f32_16x16x32_fp8_fp8(kfb[h][0], qf[h][0], aq[h], 0,0,0);
        aq[h] = __builtin_amdgcn_mfma_f32_16x16x32_fp8_fp8(kfb[h][1], qf[h][1], aq[h], 0,0,0);
      }
      #pragma unroll
      for (int r=0;r<4;r++){
        float s0=aq[0][r], s1=aq[1][r], s2=aq[2][r],
              s3=aq[3][r], s4=aq[4][r], s5=aq[5][r];
        #pragma unroll
        for (int g=0;g<6;g++){
          float sm = tbr[g*6]*s0 + tbr[g*6+1]*s1 + tbr[g*6+2]*s2
                   + tbr[g*6+3]*s3 + tbr[g*6+4]*s4 + tbr[g*6+5]*s5;
          lsum[g] += __builtin_amdgcn_exp2f(sm*SC);
        }
      }
    }
  }
  #pragma unroll
  for (int g=0;g<6;g++){
    lsum[g] += __shfl_xor(lsum[g],16);
    lsum[g] += __shfl_xor(lsum[g],32);
  }
  if (r16==0){
    #pragma unroll
    for (int g=0;g<6;g++) lred[w][g][c16] = lsum[g];
  }
  __syncthreads();      // lred visible; stageV(0) drained
  float invl[6];
  #pragma unroll
  for (int g=0;g<6;g++)
    invl[g] = 256.0f/(lred[0][g][c16]+lred[1][g][c16]+lred[2][g][c16]+lred[3][g][c16]);
  // ---------------- PASS 2: recompute + mix + PV, kf register-pipelined ----------------
  f32x4 acc[6] = {};
  int pmoff = (((w*2+(r16>>1))<<3) ^ ((c16&7)<<3)) + ((r16&1)<<2);
  v2i64 kfc[6], kfn[6];
  #pragma unroll
  for (int h=0;h<6;h++)
    kfc[h] = *(const v2i64*)(k8f + (((((size_t)(b*6+h))<<6) + ((w*16)>>4))<<10) + lane*16);
  for (int mt=0; mt<16; ++mt){
    // prefetch next tile's fragments: latency hides under this tile's VALU + PV
    if (mt<15){
      int m1 = (mt+1)*64 + w*16;
      #pragma unroll
      for (int h=0;h<6;h++)
        kfn[h] = *(const v2i64*)(k8f + (((((size_t)(b*6+h))<<6) + (m1>>4))<<10) + lane*16);
    }
    f32x4 aq[6] = {};
    #pragma unroll
    for (int h=0;h<6;h++){
      aq[h] = __builtin_amdgcn_mfma_f32_16x16x32_fp8_fp8(kfc[h][0], qf[h][0], aq[h], 0,0,0);
      aq[h] = __builtin_amdgcn_mfma_f32_16x16x32_fp8_fp8(kfc[h][1], qf[h][1], aq[h], 0,0,0);
    }
    float pm[6][4];
    #pragma unroll
    for (int r=0;r<4;r++){
      float s0=aq[0][r], s1=aq[1][r], s2=aq[2][r],
            s3=aq[3][r], s4=aq[4][r], s5=aq[5][r];
      float eg[6];
      #pragma unroll
      for (int g=0;g<6;g++){
        float sm = tbr[g*6]*s0 + tbr[g*6+1]*s1 + tbr[g*6+2]*s2
                 + tbr[g*6+3]*s3 + tbr[g*6+4]*s4 + tbr[g*6+5]*s5;
        eg[g] = __builtin_amdgcn_exp2f(sm*SC) * invl[g];   // 256*P
      }
      #pragma unroll
      for (int g2=0;g2<6;g2++)
        pm[g2][r] = tar[g2*6]*eg[0] + tar[g2*6+1]*eg[1] + tar[g2*6+2]*eg[2]
                  + tar[g2*6+3]*eg[3] + tar[g2*6+4]*eg[4] + tar[g2*6+5]*eg[5];
    }
    #pragma unroll
    for (int g2=0;g2<6;g2++){
      int d0 = __builtin_amdgcn_cvt_pk_fp8_f32(pm[g2][0], pm[g2][1], 0, false);
      d0 = __builtin_amdgcn_cvt_pk_fp8_f32(pm[g2][2], pm[g2][3], d0, true);
      *(unsigned int*)(pms + (g2*16 + c16)*72 + pmoff) = (unsigned int)d0;
    }
    __syncthreads();                 // pms complete; prior stageV drained
    #pragma unroll
    for (int g=0;g<6;g++){
      int arow = g*16 + c16;
      int vrow = g*64 + w*16 + c16;
      #pragma unroll
      for (int kk=0;kk<2;kk++){
        long af = *(const long*)(pms + arow*72 + ((kk*32 + r16*8) ^ ((c16&7)<<3)));
        long bf = *(const long*)(Vs + vrow*64
                   + ((((kk*2 + (r16>>1)) ^ (vrow&3))<<4) + ((r16&1)<<3)));
        acc[g] = __builtin_amdgcn_mfma_f32_16x16x32_fp8_fp8(af, bf, acc[g], 0,0,0);
      }
    }
    __syncthreads();                 // pms/Vs reads done
    if (mt<15) stageV((mt+1)*64);
    #pragma unroll
    for (int h=0;h<6;h++) kfc[h] = kfn[h];
  }
  #pragma unroll
  for (int g=0;g<6;g++)
    #pragma unroll
    for (int r=0;r<4;r++){
      int n = n0 + r16*4 + r;
      int d = g*64 + w*16 + c16;
      outp8[((size_t)(b*1024 + n))*DD + d] = f2f8(acc[g][r] * 0.015625f);  // /256 then x4
    }
}

extern "C" void kernel_launch(void* const* d_in, const int* in_sizes, int n_in,
                              void* d_out, int out_size, void* d_ws, size_t ws_size,
                              hipStream_t stream){
  const float* x      = (const float*)d_in[0];
  const float* qkv_w  = (const float*)d_in[1];
  const float* qkv_b  = (const float*)d_in[2];
  const float* proj_w = (const float*)d_in[3];
  const float* proj_b = (const float*)d_in[4];
  const float* t_before=(const float*)d_in[5];
  const float* t_after =(const float*)d_in[6];
  const float* dw_w   = (const float*)d_in[7];
  const float* dw_b   = (const float*)d_in[8];
  const float* mlp_g  = (const float*)d_in[9];
  const float* mlp_b  = (const float*)d_in[10];
  const float* n1_g   = (const float*)d_in[11];
  const float* n1_b   = (const float*)d_in[12];
  const float* n2_g   = (const float*)d_in[13];
  const float* n2_b   = (const float*)d_in[14];
  const float* fc1_w  = (const float*)d_in[15];
  const float* fc1_b  = (const float*)d_in[16];
  const float* fc2_w  = (const float*)d_in[17];
  const float* fc2_b  = (const float*)d_in[18];
  float* out = (float*)d_out;
  char* ws = (char*)d_ws;
  unsigned char*  qkvw8 = (unsigned char*)(ws + 0);           // 442368
  unsigned char*  projw8= (unsigned char*)(ws + 442368);      // 147456
  unsigned char*  fc1w8 = (unsigned char*)(ws + 589824);      // 589824
  unsigned char*  fc2w8 = (unsigned char*)(ws + 1179648);     // 589824
  unsigned char*  hb8   = (unsigned char*)(ws + 1769472);     // 8192*384 fp8 (reuse: hcln8)
  unsigned char*  qk8   = (unsigned char*)(ws + 4915200);     // 2*SEC fp8 frag planes (reuse: h2 bf16)
  unsigned char*  V8    = (unsigned char*)(ws + 11206656);    // 48*64*1024 fp8
  unsigned char*  fc1o8 = (unsigned char*)(ws + 14745600);    // 8192*1536 fp8
  unsigned char*  attnb8= (unsigned char*)(ws + 65077248);    // 8192*384 fp8
  float*          x2    = (float*)        (ws + 68222976);    // 8192*384 f32
  unsigned short* h2 = (unsigned short*)qk8;
  unsigned char*  hcln8 = hb8;

  cvt_kernel<<<6912,256,0,stream>>>(qkv_w, proj_w, fc1_w, fc2_w, qkvw8);

  ln_kernel<1><<<BN,128,0,stream>>>(x, n1_g, n1_b, nullptr, hb8);
  { dim3 g(BN/64, D3/64); gemm8_kernel<0><<<g,256,0,stream>>>(hb8, qkvw8, qkv_b, nullptr, nullptr, nullptr, qk8, V8, DD, D3); }
  fattn8_kernel<<<512,256,0,stream>>>(qk8, V8, t_before, t_after, attnb8);
  { dim3 g(BN/64, DD/64); gemm8_kernel<1><<<g,256,0,stream>>>(attnb8, projw8, proj_b, x, x2, nullptr, nullptr, nullptr, DD, DD); }
  ln_kernel<0><<<BN,128,0,stream>>>(x2, n2_g, n2_b, h2, nullptr);
  conv_ln_kernel<<<BN,128,0,stream>>>(h2, dw_w, dw_b, mlp_g, mlp_b, hcln8);
  { dim3 g(BN/64, D4/64); gemm8_kernel<2><<<g,256,0,stream>>>(hcln8, fc1w8, fc1_b, nullptr, nullptr, fc1o8, nullptr, nullptr, DD, D4); }
  { dim3 g(BN/64, DD/64); gemm8_kernel<1><<<g,256,0,stream>>>(fc1o8, fc2w8, fc2_b, x2, out, nullptr, nullptr, nullptr, D4, DD); }
}